// Round 1
// baseline (25.970 us; speedup 1.0000x reference)
//
#include <hip/hip_runtime.h>
#include <math.h>

#define BB 512
#define NN 512
#define DD 128
#define S_CHUNKS 4
#define CHUNK (NN / S_CHUNKS)     // 128 rows per chunk
#define PSTRIDE 132               // floats per partial slot: 128 s + 1 t, padded (16B mult)

// Kernel 1: per (b, chunk) block computes partial weighted sum s[d] and gate sum t.
//   s[b,d] = sum_{n in chunk, n < ns[b]} sigmoid(h[b,n]*W_g + b_g) * h[b,n,d]
// 256 threads = 8 row-groups of 32 lanes; each group handles rows grp, grp+8, ...
// float4 loads: one wave64 (2 groups, adjacent rows) reads 1024 contiguous bytes.
__global__ __launch_bounds__(256) void k1_partial(
    const float* __restrict__ h,
    const int*   __restrict__ ns,
    const float* __restrict__ W_g,
    const float* __restrict__ b_g,
    float*       __restrict__ part)
{
    const int bc   = blockIdx.x;
    const int b    = bc / S_CHUNKS;
    const int c    = bc % S_CHUNKS;
    const int tid  = threadIdx.x;
    const int grp  = tid >> 5;
    const int lane = tid & 31;

    const int nsb   = ns[b];
    const int start = c * CHUNK;
    const int end   = min(start + CHUNK, nsb);

    __shared__ float lds_s[8 * 128];
    __shared__ float lds_t[8];

    // W_g fragment for this lane (dims lane*4 .. lane*4+3), loaded once
    const float4 wg = ((const float4*)W_g)[lane];
    const float  bg = b_g[0];

    float4 acc  = make_float4(0.f, 0.f, 0.f, 0.f);
    float  tacc = 0.f;

    for (int n = start + grp; n < end; n += 8) {
        const float4 v = ((const float4*)(h + ((size_t)b * NN + (size_t)n) * DD))[lane];
        float d = v.x * wg.x + v.y * wg.y + v.z * wg.z + v.w * wg.w;
        // butterfly reduce within the 32-lane group (masks < 32 stay in-half)
        d += __shfl_xor(d, 1);
        d += __shfl_xor(d, 2);
        d += __shfl_xor(d, 4);
        d += __shfl_xor(d, 8);
        d += __shfl_xor(d, 16);
        const float g = 1.f / (1.f + expf(-(d + bg)));
        acc.x += g * v.x;
        acc.y += g * v.y;
        acc.z += g * v.z;
        acc.w += g * v.w;
        tacc  += g;   // same value on all 32 lanes of the group
    }

    // cross-group reduction via LDS
    ((float4*)lds_s)[grp * 32 + lane] = acc;
    if (lane == 0) lds_t[grp] = tacc;
    __syncthreads();

    float* pout = part + (size_t)bc * PSTRIDE;
    if (tid < 128) {
        float s = 0.f;
        #pragma unroll
        for (int g2 = 0; g2 < 8; ++g2) s += lds_s[g2 * 128 + tid];
        pout[tid] = s;           // always written (zeros if chunk inactive) -> deterministic ws
    }
    if (tid == 0) {
        float t = 0.f;
        #pragma unroll
        for (int g2 = 0; g2 < 8; ++g2) t += lds_t[g2];
        pout[128] = t;
    }
}

// Kernel 2: per-b block, 128 threads (thread e = output dim).
//   hG[e] = W_f[e,:] . s[b,:] + t[b] * b_f[e];  out = hG / max(||hG||, eps)
__global__ __launch_bounds__(128) void k2_final(
    const float* __restrict__ part,
    const float* __restrict__ W_f,
    const float* __restrict__ b_f,
    float*       __restrict__ out)
{
    const int b = blockIdx.x;
    const int e = threadIdx.x;

    __shared__ float s_lds[128];
    __shared__ float red[2];

    const float* pb = part + (size_t)b * S_CHUNKS * PSTRIDE;

    float s = 0.f;
    #pragma unroll
    for (int c = 0; c < S_CHUNKS; ++c) s += pb[c * PSTRIDE + e];
    s_lds[e] = s;

    float t = 0.f;
    #pragma unroll
    for (int c = 0; c < S_CHUNKS; ++c) t += pb[c * PSTRIDE + 128];  // broadcast loads
    __syncthreads();

    float hg = t * b_f[e];
    const float4* wrow = (const float4*)(W_f + (size_t)e * DD);
    const float4* sv   = (const float4*)s_lds;
    #pragma unroll 8
    for (int k = 0; k < 32; ++k) {
        const float4 w  = wrow[k];
        const float4 sk = sv[k];   // LDS broadcast, conflict-free
        hg += w.x * sk.x + w.y * sk.y + w.z * sk.z + w.w * sk.w;
    }

    // sum of squares across 128 threads = 2 waves
    float sq = hg * hg;
    sq += __shfl_xor(sq, 1);
    sq += __shfl_xor(sq, 2);
    sq += __shfl_xor(sq, 4);
    sq += __shfl_xor(sq, 8);
    sq += __shfl_xor(sq, 16);
    sq += __shfl_xor(sq, 32);
    if ((threadIdx.x & 63) == 0) red[threadIdx.x >> 6] = sq;
    __syncthreads();

    const float norm = sqrtf(red[0] + red[1]);
    out[(size_t)b * DD + e] = hg / fmaxf(norm, 1e-12f);
}

extern "C" void kernel_launch(void* const* d_in, const int* in_sizes, int n_in,
                              void* d_out, int out_size, void* d_ws, size_t ws_size,
                              hipStream_t stream) {
    const float* h   = (const float*)d_in[0];
    const int*   ns  = (const int*)  d_in[1];
    const float* W_f = (const float*)d_in[2];
    const float* b_f = (const float*)d_in[3];
    const float* W_g = (const float*)d_in[4];
    const float* b_g = (const float*)d_in[5];
    float* out  = (float*)d_out;
    float* part = (float*)d_ws;   // BB * S_CHUNKS * PSTRIDE floats ~ 1.06 MB

    k1_partial<<<BB * S_CHUNKS, 256, 0, stream>>>(h, ns, W_g, b_g, part);
    k2_final<<<BB, 128, 0, stream>>>(part, W_f, b_f, out);
}